// Round 4
// baseline (1515.012 us; speedup 1.0000x reference)
//
#include <hip/hip_runtime.h>
#include <hip/hip_bf16.h>
#include <cstdint>
#include <cstddef>

#define ALPHA 0.02f
static constexpr int B_ = 2, F_ = 768, I_ = 1536, E_ = 8, S_ = 1024;
static constexpr int O3I = 3 * I_;      // 4608
static constexpr int NTOK = B_ * S_;    // 2048

__device__ __forceinline__ float waveSum(float v) {
  #pragma unroll
  for (int off = 32; off; off >>= 1) v += __shfl_xor(v, off);
  return v;
}
__device__ __forceinline__ double waveSumD(double v) {
  #pragma unroll
  for (int off = 32; off; off >>= 1) v += __shfl_xor(v, off);
  return v;
}

__global__ __launch_bounds__(64) void zero_meta(float* gs0, float* gs2, int* cnt0, int* cnt2) {
  int i = threadIdx.x;
  if (i < 8) { gs0[i] = 0.f; gs2[i] = 0.f; cnt0[i] = 0; cnt2[i] = 0; }
}

// ---------------- gate 0: logits (fp64) -> softmax/argmax -> bucket ----------------
__global__ __launch_bounds__(256) void gate0_kernel(const float* __restrict__ x, const float* __restrict__ wg,
                                                    float* __restrict__ gs, int* __restrict__ cnt,
                                                    int* __restrict__ bucket) {
  const int tk = threadIdx.x & 63;       // token lane (coalesced over s)
  const int cpart = threadIdx.x >> 6;    // 4-way split over channels
  const int t = blockIdx.x * 64 + tk;
  const int b = t >> 10, s = t & 1023;
  double l[8] = {0,0,0,0,0,0,0,0};
  const float* xb = x + (size_t)b * F_ * S_ + s;
  for (int c = cpart * 192; c < cpart * 192 + 192; ++c) {
    double xv = (double)xb[(size_t)c * S_];
    const float* w = wg + c * 8;
    #pragma unroll
    for (int e = 0; e < 8; ++e) l[e] += xv * (double)w[e];
  }
  __shared__ double red[4][8][64];
  #pragma unroll
  for (int e = 0; e < 8; ++e) red[cpart][e][tk] = l[e];
  __syncthreads();
  if (cpart == 0) {
    double lg[8]; double m = -1e300; int am = 0;
    #pragma unroll
    for (int e = 0; e < 8; ++e) {
      lg[e] = red[0][e][tk] + red[1][e][tk] + red[2][e][tk] + red[3][e][tk];
      if (lg[e] > m) { m = lg[e]; am = e; }   // strict > keeps first max (jnp.argmax)
    }
    float den = 0.f;
    #pragma unroll
    for (int e = 0; e < 8; ++e) den += expf((float)(lg[e] - m));
    float inv = 1.f / den;
    #pragma unroll
    for (int e = 0; e < 8; ++e) atomicAdd(&gs[e], expf((float)(lg[e] - m)) * inv);
    int slot = atomicAdd(&cnt[am], 1);
    bucket[am * NTOK + slot] = t;
  }
}

// ---------------- gate 2 (token-major input, fp64 logits) ----------------
__global__ __launch_bounds__(256) void gate2_kernel(const float* __restrict__ hb, const float* __restrict__ wg,
                                                    float* __restrict__ gs, int* __restrict__ cnt,
                                                    int* __restrict__ bucket) {
  const int t = blockIdx.x;
  const float* p = hb + (size_t)t * I_;
  double l[8] = {0,0,0,0,0,0,0,0};
  #pragma unroll
  for (int r = 0; r < 6; ++r) {
    int i = threadIdx.x + r * 256;
    double xv = (double)p[i];
    const float* w = wg + i * 8;
    #pragma unroll
    for (int e = 0; e < 8; ++e) l[e] += xv * (double)w[e];
  }
  __shared__ double red[8][4];
  #pragma unroll
  for (int e = 0; e < 8; ++e) {
    double v = waveSumD(l[e]);
    if ((threadIdx.x & 63) == 0) red[e][threadIdx.x >> 6] = v;
  }
  __syncthreads();
  if (threadIdx.x == 0) {
    double lg[8]; double m = -1e300; int am = 0;
    #pragma unroll
    for (int e = 0; e < 8; ++e) {
      lg[e] = red[e][0] + red[e][1] + red[e][2] + red[e][3];
      if (lg[e] > m) { m = lg[e]; am = e; }
    }
    float den = 0.f;
    #pragma unroll
    for (int e = 0; e < 8; ++e) den += expf((float)(lg[e] - m));
    float inv = 1.f / den;
    #pragma unroll
    for (int e = 0; e < 8; ++e) atomicAdd(&gs[e], expf((float)(lg[e] - m)) * inv);
    int slot = atomicAdd(&cnt[am], 1);
    bucket[am * NTOK + slot] = t;
  }
}

// ---------------- grouped gather-GEMM (per-expert) ----------------
// block: 64 tokens x 128 outputs, thread-tile 4 tok x 8 out, C-chunks of 16 staged in LDS
// DACC: fp64 accumulation (needed for MoE0: scale/shift feed an ill-conditioned
//       divisor d=(s+1)*scale+shift downstream; fp32 sum noise flips sign(d))
template<int C, int O, bool IN_TM, bool OUT_TM, bool DACC>
__global__ __launch_bounds__(256) void moe_gemm(const float* __restrict__ inp, const float* __restrict__ w,
                                                const int* __restrict__ cnt, const int* __restrict__ bucket,
                                                float* __restrict__ out) {
  using AccT = typename std::conditional<DACC, double, float>::type;
  const int e = blockIdx.y;
  const int n = cnt[e];
  const int t0 = blockIdx.z * 64;
  if (t0 >= n) return;
  const int ob = blockIdx.x * 128;
  const int tid = threadIdx.x;
  const int o_t = tid & 15;
  const int t_t = tid >> 4;
  __shared__ float xs[16][64];
  __shared__ float wsh[16][128];
  __shared__ int toks[64];
  __shared__ int bases[64];
  if (tid < 64) {
    int idx = t0 + tid;
    int tt = (idx < n) ? bucket[e * NTOK + idx] : -1;
    toks[tid] = tt;
    if (tt >= 0) {
      int b = tt >> 10, s = tt & 1023;
      bases[tid] = IN_TM ? tt * C : b * C * S_ + s;
    } else bases[tid] = -1;
  }
  __syncthreads();
  AccT acc[4][8];
  #pragma unroll
  for (int i = 0; i < 4; ++i)
    #pragma unroll
    for (int j = 0; j < 8; ++j) acc[i][j] = (AccT)0;
  const float* wE = w + (size_t)e * C * O + ob;
  for (int c0 = 0; c0 < C; c0 += 16) {
    #pragma unroll
    for (int r = 0; r < 4; ++r) {
      int idx = r * 256 + tid;
      int cc = idx >> 6, tk = idx & 63;
      int bs = bases[tk];
      xs[cc][tk] = (bs >= 0) ? inp[(size_t)bs + (size_t)(c0 + cc) * (IN_TM ? 1 : S_)] : 0.f;
    }
    #pragma unroll
    for (int r = 0; r < 8; ++r) {
      int idx = r * 256 + tid;
      int cc = idx >> 7, oo = idx & 127;
      wsh[cc][oo] = wE[(size_t)(c0 + cc) * O + oo];
    }
    __syncthreads();
    #pragma unroll
    for (int cc = 0; cc < 16; ++cc) {
      float4 av = *reinterpret_cast<const float4*>(&xs[cc][t_t * 4]);
      float4 b0 = *reinterpret_cast<const float4*>(&wsh[cc][o_t * 8]);
      float4 b1 = *reinterpret_cast<const float4*>(&wsh[cc][o_t * 8 + 4]);
      AccT a[4] = {(AccT)av.x, (AccT)av.y, (AccT)av.z, (AccT)av.w};
      AccT bv[8] = {(AccT)b0.x, (AccT)b0.y, (AccT)b0.z, (AccT)b0.w,
                    (AccT)b1.x, (AccT)b1.y, (AccT)b1.z, (AccT)b1.w};
      #pragma unroll
      for (int i = 0; i < 4; ++i)
        #pragma unroll
        for (int j = 0; j < 8; ++j) acc[i][j] += a[i] * bv[j];
    }
    __syncthreads();
  }
  #pragma unroll
  for (int i = 0; i < 4; ++i) {
    int tk = t_t * 4 + i;
    int tt = toks[tk];
    if (tt < 0) continue;
    if (OUT_TM) {
      float* op = out + (size_t)tt * O + ob + o_t * 8;
      float4 v0 = {(float)acc[i][0], (float)acc[i][1], (float)acc[i][2], (float)acc[i][3]};
      float4 v1 = {(float)acc[i][4], (float)acc[i][5], (float)acc[i][6], (float)acc[i][7]};
      *reinterpret_cast<float4*>(op) = v0;
      *reinterpret_cast<float4*>(op + 4) = v1;
    } else {
      int b = tt >> 10, s = tt & 1023;
      #pragma unroll
      for (int j = 0; j < 8; ++j)
        out[((size_t)b * O + ob + o_t * 8 + j) * S_ + s] = (float)acc[i][j];
    }
  }
}

// ---------------- chunked cumsum over s (3 phases) + fp64 divide ----------------
__global__ __launch_bounds__(256) void cumsum_partial(const float* __restrict__ h0, float* __restrict__ part) {
  const int i = blockIdx.x * 256 + threadIdx.x;       // channel 0..1535
  const int chunk = blockIdx.y, b = blockIdx.z;
  float sum = 0.f;
  const float* base = h0 + ((size_t)(b * S_ + chunk * 128)) * O3I + i;
  for (int s = 0; s < 128; ++s) sum += base[(size_t)s * O3I];
  part[((size_t)(b * 8 + chunk)) * I_ + i] = sum;
}

__global__ __launch_bounds__(256) void cumsum_scan(float* part) {
  const int idx = blockIdx.x * 256 + threadIdx.x;     // 0..3071 = b*1536+i
  const int b = idx / 1536, i = idx - b * 1536;
  float run = 0.f;
  #pragma unroll
  for (int c = 0; c < 8; ++c) {
    size_t p = ((size_t)(b * 8 + c)) * I_ + i;
    float v = part[p]; part[p] = run; run += v;
  }
}

__global__ __launch_bounds__(256) void cumsum_apply(const float* __restrict__ h0, const float* __restrict__ part,
                                                    float* __restrict__ y) {
  const int i = blockIdx.x * 256 + threadIdx.x;
  const int chunk = blockIdx.y, b = blockIdx.z;
  float run = part[((size_t)(b * 8 + chunk)) * I_ + i];
  for (int s = chunk * 128; s < chunk * 128 + 128; ++s) {
    const float* row = h0 + ((size_t)(b * S_ + s)) * O3I;
    run += row[i];
    // d is catastrophically cancellative: compute in fp64 so sign(d) matches the fp64 ref
    double d = (double)(s + 1) * (double)row[I_ + i] + (double)row[2 * I_ + i];
    y[((size_t)(b * S_ + s)) * I_ + i] = (float)((double)run / d);
  }
}

// ---------------- per-token rmsnorm + leaky (in place) ----------------
__global__ __launch_bounds__(256) void rmsnorm_leaky_kernel(float* __restrict__ buf) {
  const int t = blockIdx.x;
  float* p = buf + (size_t)t * I_;
  float v[6]; float ssum = 0.f;
  #pragma unroll
  for (int r = 0; r < 6; ++r) { v[r] = p[threadIdx.x + r * 256]; ssum += v[r] * v[r]; }
  ssum = waveSum(ssum);
  __shared__ float red[4];
  if ((threadIdx.x & 63) == 0) red[threadIdx.x >> 6] = ssum;
  __syncthreads();
  float tot = red[0] + red[1] + red[2] + red[3];
  float rs = rsqrtf(tot * (1.f / I_) + 1e-6f);
  #pragma unroll
  for (int r = 0; r < 6; ++r) {
    float y = v[r] * rs;
    p[threadIdx.x + r * 256] = y > 0.f ? y : ALPHA * y;
  }
}

// ---------------- split-norm: leaky(rmsnorm(s0*s1+sh)) ----------------
__global__ __launch_bounds__(256) void split_norm_kernel(const float* __restrict__ hc, float* __restrict__ hb) {
  const int t = blockIdx.x;
  const float* p = hc + (size_t)t * O3I;
  float z[6]; float ssum = 0.f;
  #pragma unroll
  for (int r = 0; r < 6; ++r) {
    int i = threadIdx.x + r * 256;
    float zz = p[i] * p[I_ + i] + p[2 * I_ + i];
    z[r] = zz; ssum += zz * zz;
  }
  ssum = waveSum(ssum);
  __shared__ float red[4];
  if ((threadIdx.x & 63) == 0) red[threadIdx.x >> 6] = ssum;
  __syncthreads();
  float tot = red[0] + red[1] + red[2] + red[3];
  float rs = rsqrtf(tot * (1.f / I_) + 1e-6f);
  #pragma unroll
  for (int r = 0; r < 6; ++r) {
    float y = z[r] * rs;
    hb[(size_t)t * I_ + threadIdx.x + r * 256] = y > 0.f ? y : ALPHA * y;
  }
}

// ---------------- grouped causal conv1d: [B,S,I] -> [B,S,3I] ----------------
__global__ __launch_bounds__(256) void conv_kernel(const float* __restrict__ xin, const float* __restrict__ w1,
                                                   float* __restrict__ out) {
  const int bs = blockIdx.x;            // 0..63 = b*32 + s_tile
  const int b = bs >> 5;
  const int s0 = (bs & 31) * 32;
  const int ob = blockIdx.y * 64;       // output-channel tile (64 | 576 group size)
  const int g = ob / 576;
  const int tid = threadIdx.x;
  const int ss = tid >> 6;              // 4 sub-tiles of 8 s-positions
  const int ol = tid & 63;
  const int o = ob + ol;
  __shared__ float xl[192][40];         // [ci][s-window 36, pad to 40]
  for (int idx = tid; idx < 36 * 192; idx += 256) {
    int sl = idx / 192, ci = idx % 192;
    int s = s0 - 4 + sl;
    xl[ci][sl] = (s >= 0) ? xin[((size_t)(b * S_ + s)) * I_ + g * 192 + ci] : 0.f;
  }
  __syncthreads();
  float acc[8] = {0.f,0.f,0.f,0.f,0.f,0.f,0.f,0.f};
  const float* wb = w1 + o;
  for (int ci = 0; ci < 192; ++ci) {
    const float4* xr = reinterpret_cast<const float4*>(&xl[ci][ss * 8]);
    float4 v0 = xr[0], v1 = xr[1], v2 = xr[2];
    float xw[12] = {v0.x, v0.y, v0.z, v0.w, v1.x, v1.y, v1.z, v1.w, v2.x, v2.y, v2.z, v2.w};
    #pragma unroll
    for (int k = 0; k < 5; ++k) {
      float wv = wb[(size_t)(k * 192 + ci) * O3I];
      #pragma unroll
      for (int j = 0; j < 8; ++j) acc[j] += xw[j + k] * wv;
    }
  }
  float* op = out + ((size_t)(b * S_ + s0 + ss * 8)) * O3I + o;
  #pragma unroll
  for (int j = 0; j < 8; ++j) op[(size_t)j * O3I] = acc[j];
}

__global__ void finalize_loss(const float* gs0, const int* cnt0, const float* gs2, const int* cnt2,
                              float* outp) {
  float l = 0.f;
  for (int e = 0; e < 8; ++e) l += gs0[e] * (float)cnt0[e] + gs2[e] * (float)cnt2[e];
  *outp = l * (1.f / ((float)NTOK * (float)NTOK));
}

extern "C" void kernel_launch(void* const* d_in, const int* in_sizes, int n_in,
                              void* d_out, int out_size, void* d_ws, size_t ws_size,
                              hipStream_t stream) {
  const float* x   = (const float*)d_in[0];
  const float* w0g = (const float*)d_in[1];
  const float* w0  = (const float*)d_in[2];
  const float* w1  = (const float*)d_in[3];
  const float* w2g = (const float*)d_in[4];
  const float* w2  = (const float*)d_in[5];
  float* out = (float*)d_out;

  char* ws = (char*)d_ws;
  // bufA: [2048, 4608] f32 (MoE0 out, then conv out); bufB: [2048, 1536] f32
  float* bufA    = (float*)ws;                        // 37,748,736 B
  float* bufB    = (float*)(ws + 37748736);           // 12,582,912 B
  float* part    = (float*)(ws + 50331648);           //     98,304 B
  float* gs0     = (float*)(ws + 50429952);
  float* gs2     = (float*)(ws + 50429952 + 32);
  int*   cnt0    = (int*)(ws + 50430016);
  int*   cnt2    = (int*)(ws + 50430048);
  int*   bucket0 = (int*)(ws + 50430080);             // 65,536 B
  int*   bucket2 = (int*)(ws + 50495616);             // 65,536 B

  zero_meta<<<1, 64, 0, stream>>>(gs0, gs2, cnt0, cnt2);
  gate0_kernel<<<32, 256, 0, stream>>>(x, w0g, gs0, cnt0, bucket0);
  moe_gemm<F_, O3I, false, true, true><<<dim3(36, 8, 32), 256, 0, stream>>>(x, w0, cnt0, bucket0, bufA);
  cumsum_partial<<<dim3(6, 8, 2), 256, 0, stream>>>(bufA, part);
  cumsum_scan<<<12, 256, 0, stream>>>(part);
  cumsum_apply<<<dim3(6, 8, 2), 256, 0, stream>>>(bufA, part, bufB);
  rmsnorm_leaky_kernel<<<NTOK, 256, 0, stream>>>(bufB);
  conv_kernel<<<dim3(64, 72), 256, 0, stream>>>(bufB, w1, bufA);
  split_norm_kernel<<<NTOK, 256, 0, stream>>>(bufA, bufB);
  gate2_kernel<<<NTOK, 256, 0, stream>>>(bufB, w2g, gs2, cnt2, bucket2);
  moe_gemm<I_, F_, true, false, false><<<dim3(6, 8, 32), 256, 0, stream>>>(bufB, w2, cnt2, bucket2, out);
  finalize_loss<<<1, 1, 0, stream>>>(gs0, cnt0, gs2, cnt2, out + (size_t)B_ * F_ * S_);
}